// Round 10
// baseline (129.219 us; speedup 1.0000x reference)
//
#include <hip/hip_runtime.h>
#include <cstddef>

typedef _Float16 f16_t;
typedef _Float16 f16x8 __attribute__((ext_vector_type(8)));
typedef float    f32x4  __attribute__((ext_vector_type(4)));
typedef float    f32x16 __attribute__((ext_vector_type(16)));

static constexpr int NN = 64;    // nodes
static constexpr int FF = 4;     // features
static constexpr int HH = 256;   // hidden

// ---- workspace layout (bytes) ----
// W2p    @ 0        : 131072   (W_msg2 packed 32x32x16 B-frags, f16)
// W1op   @ 131072   : 147456   (W_out1 padded/remapped 16x16x32, f16)
// W2op   @ 278528   : 131072   (W_out2 packed 16x16x32, f16)
// innode @ 409600   : 4718592  ([agg(256) | x(4) | pad(28)] f16, 8192 rows)
// Vp     @ 5128192  : 4194304  (V = x @ W1[4:8], f16 [128][64][256])
// Up     @ 9322496  : 4194304  (U = x @ W1[0:4] + b1, f16 [128][64][256])

// ------------------------------------------------------------------
// 16x16x32 B-frag pack: lane holds B[k=ks*32+(lane>>4)*8+j][col=nt*16+(lane&15)]
// ------------------------------------------------------------------
__device__ inline void pack_frag16(const float* __restrict__ src, f16_t* __restrict__ dst,
                                   int fid, int ksteps, int mode)
{
    if (fid >= ksteps * 1024) return;
    int lane = fid & 63;
    int nt   = (fid >> 6) & 15;
    int ks   = fid >> 10;
    int col  = nt * 16 + (lane & 15);
    int kb   = ks * 32 + (lane >> 4) * 8;
    #pragma unroll
    for (int j = 0; j < 8; ++j) {
        int k = kb + j;
        float v;
        if (mode == 0) {
            v = src[k * 256 + col];
        } else {
            if (k < 256)      v = src[(4 + k) * 256 + col];
            else if (k < 260) v = src[(k - 256) * 256 + col];
            else              v = 0.f;
        }
        dst[(size_t)fid * 8 + j] = (f16_t)v;
    }
}

// ------------------------------------------------------------------
// 32x32x16 B-frag pack: lane holds B[k=ks*16+(lane>>5)*8+j][col=nt*32+(lane&31)]
// ------------------------------------------------------------------
__device__ inline void pack_frag32(const float* __restrict__ src, f16_t* __restrict__ dst,
                                   int fid)
{
    int lane = fid & 63;
    int nt   = (fid >> 6) & 7;
    int ks   = fid >> 9;
    int col  = nt * 32 + (lane & 31);
    int kb   = ks * 16 + (lane >> 5) * 8;
    #pragma unroll
    for (int j = 0; j < 8; ++j)
        dst[(size_t)fid * 8 + j] = (f16_t)src[(kb + j) * 256 + col];
}

// ------------------------------------------------------------------
// Fused prep: weight packs + U/V precompute + innode x-tail.
// ------------------------------------------------------------------
__global__ void prep_all(const float* __restrict__ x,
                         const float* __restrict__ W_msg1,
                         const float* __restrict__ b_msg1,
                         const float* __restrict__ W_msg2,
                         const float* __restrict__ W_out1,
                         const float* __restrict__ W_out2,
                         f16_t* __restrict__ W2p, f16_t* __restrict__ W1op,
                         f16_t* __restrict__ W2op, f16_t* __restrict__ Vp,
                         f16_t* __restrict__ Up, f16_t* __restrict__ innode)
{
    int bid = blockIdx.x, tid = threadIdx.x;
    if (bid < 32) {
        pack_frag32(W_msg2, W2p, bid * 256 + tid);
    } else if (bid < 68) {
        pack_frag16(W_out1, W1op, (bid - 32) * 256 + tid, 9, 1);
    } else if (bid < 100) {
        pack_frag16(W_out2, W2op, (bid - 68) * 256 + tid, 8, 0);
    } else {
        int gid  = (bid - 100) * 256 + tid;   // 262144
        int rown = gid >> 5;                   // b*64+n
        int hb   = gid & 31;
        int h0   = hb * 8;
        float4 xv = ((const float4*)x)[rown];
        f16x8 ov, ou;
        #pragma unroll
        for (int u = 0; u < 8; ++u) {
            int h = h0 + u;
            float sv = xv.x * W_msg1[4 * HH + h] + xv.y * W_msg1[5 * HH + h]
                     + xv.z * W_msg1[6 * HH + h] + xv.w * W_msg1[7 * HH + h];
            float su = b_msg1[h]
                     + xv.x * W_msg1[0 * HH + h] + xv.y * W_msg1[1 * HH + h]
                     + xv.z * W_msg1[2 * HH + h] + xv.w * W_msg1[3 * HH + h];
            ov[u] = (f16_t)sv;
            ou[u] = (f16_t)su;
        }
        *(f16x8*)(Vp + (size_t)rown * HH + h0) = ov;
        *(f16x8*)(Up + (size_t)rown * HH + h0) = ou;
        float xt = (hb < 4) ? ((const float*)&xv)[hb] : 0.f;
        innode[(size_t)rown * 288 + 256 + hb] = (f16_t)xt;
    }
}

// ------------------------------------------------------------------
// Edge MLP + aggregation — symmetric 2-stage wave-group pipeline.
// 2048 blocks x 512 threads (8 waves), 1 block/CU, LDS = 2 x 64 KB.
// Block owns 4 receivers (2 pairs) of batch b.
//   Stage A: all 8 waves build pair0 h1 -> bufA.            (barrier)
//   Stage B: waves 0-3 GEMM pair0 (MFMA pipe) WHILE waves
//            4-7 build pair1 -> bufB (VALU pipe). Each SIMD
//            holds one wave of each kind -> m114 co-issue.   (barrier)
//   Stage C: waves 0-3 epilogue pair0 (VALU) WHILE waves
//            4-7 GEMM pair1, then their epilogue.
// Overlap is cross-wave (hardware), not compiler-scheduled: no
// aliasing ordering (R7) and no shared-register-cap spill (R8 —
// launch_bounds(512,1) gives 256 VGPR/wave).
// h1[r] = relu(U[recv] + V[j]) from precomputed Up/Vp; self rows
// zeroed; agg -= relu(b2). Swizzle chunk^(r&31): PMC 0 conflicts.
// GEMM wave = 4mt x 2nt, mfma_f32_32x32x16_f16, bias in C-init.
// ------------------------------------------------------------------
__global__ __launch_bounds__(512, 1) void edge_kernel(
    const f16_t* __restrict__ Vp,     // [128][64][256]
    const f16_t* __restrict__ Up,     // [128][64][256]
    const f16_t* __restrict__ W2p,    // packed 32x32
    const float* __restrict__ b2,     // [256]
    f16_t* __restrict__ innode)       // [8192][288]
{
    __shared__ __align__(16) char bufA[128 * 512];
    __shared__ __align__(16) char bufB[128 * 512];

    const int tid  = threadIdx.x;
    const int lane = tid & 63;
    const int w    = tid >> 6;                 // 0..7
    const int grp  = w >> 2;                   // 0 = pair0, 1 = pair1
    const int b     = blockIdx.x >> 4;
    const int ibase = (blockIdx.x & 15) * 4;   // receivers ibase..ibase+3

    const f16x8 fz = {};
    const f16x8* vbase = (const f16x8*)(Vp + (size_t)(b * NN) * HH);  // [64][32]
    const f16x8* ubase = (const f16x8*)(Up + (size_t)(b * NN) * HH);

    // GEMM / epilogue lane mapping
    const int wn = w & 3;
    const int ln = lane & 31;
    const int kh = lane >> 5;
    float b2v[2];
    #pragma unroll
    for (int nt = 0; nt < 2; ++nt) b2v[nt] = b2[(wn * 2 + nt) * 32 + ln];

    // ---- stage A: all 8 waves build pair0 (recv ibase, ibase+1) -> bufA ----
    {
        const int hb = tid & 15;
        const int rg = tid >> 4;               // 0..31 -> rows rg*4..+3
        const int recv = ibase + (rg >> 4);
        f16x8 u8[2] = { ubase[recv * 32 + hb], ubase[recv * 32 + 16 + hb] };
        #pragma unroll
        for (int rr = 0; rr < 4; ++rr) {
            int r = rg * 4 + rr;               // 0..127
            int j = r & 63;                    // sender
            #pragma unroll
            for (int half = 0; half < 2; ++half) {
                f16x8 v8 = vbase[j * 32 + half * 16 + hb];
                f16x8 hv = __builtin_elementwise_max(u8[half] + v8, fz);
                if (j == recv) hv = fz;        // self edge
                int c = half * 16 + hb;
                *(f16x8*)(bufA + r * 512 + (((c ^ (r & 31)) & 31) << 4)) = hv;
            }
        }
    }
    __syncthreads();

    // accumulators (bias in C-init)
    f32x16 acc[4][2];
    #pragma unroll
    for (int mt = 0; mt < 4; ++mt)
        #pragma unroll
        for (int nt = 0; nt < 2; ++nt)
            #pragma unroll
            for (int e = 0; e < 16; ++e) acc[mt][nt][e] = b2v[nt];

    auto do_gemm = [&](const char* __restrict__ rb) {
        __builtin_amdgcn_s_setprio(1);
        f16x8 bbn0 = *(const f16x8*)(W2p + (size_t)((wn * 2 + 0) * 64 + lane) * 8);
        f16x8 bbn1 = *(const f16x8*)(W2p + (size_t)((wn * 2 + 1) * 64 + lane) * 8);
        #pragma unroll
        for (int ks = 0; ks < 16; ++ks) {
            f16x8 bb0 = bbn0, bb1 = bbn1;
            if (ks < 15) {
                bbn0 = *(const f16x8*)(W2p + (size_t)(((ks + 1) * 8 + wn * 2 + 0) * 64 + lane) * 8);
                bbn1 = *(const f16x8*)(W2p + (size_t)(((ks + 1) * 8 + wn * 2 + 1) * 64 + lane) * 8);
            }
            #pragma unroll
            for (int mt = 0; mt < 4; ++mt) {
                int row = mt * 32 + ln;
                int c16 = (ks * 2 + kh) ^ ln;  // row&31 == ln
                f16x8 a = *(const f16x8*)(rb + row * 512 + (c16 << 4));
                acc[mt][0] = __builtin_amdgcn_mfma_f32_32x32x16_f16(a, bb0, acc[mt][0], 0, 0, 0);
                acc[mt][1] = __builtin_amdgcn_mfma_f32_32x32x16_f16(a, bb1, acc[mt][1], 0, 0, 0);
            }
        }
        __builtin_amdgcn_s_setprio(0);
    };

    // ---- stage B: grp0 GEMM(pair0) | grp1 build pair1 -> bufB ----
    if (grp == 0) {
        do_gemm(bufA);
    } else {
        const int tid2 = tid - 256;
        const int hb = tid2 & 15;
        const int rg = tid2 >> 4;              // 0..15 -> rows rg*8..+7
        const int recv = ibase + 2 + (rg >> 3);
        f16x8 u8[2] = { ubase[recv * 32 + hb], ubase[recv * 32 + 16 + hb] };
        #pragma unroll
        for (int k = 0; k < 8; ++k) {
            int r = rg * 8 + k;
            int j = r & 63;
            #pragma unroll
            for (int half = 0; half < 2; ++half) {
                f16x8 v8 = vbase[j * 32 + half * 16 + hb];
                f16x8 hv = __builtin_elementwise_max(u8[half] + v8, fz);
                if (j == recv) hv = fz;
                int c = half * 16 + hb;
                *(f16x8*)(bufB + r * 512 + (((c ^ (r & 31)) & 31) << 4)) = hv;
            }
        }
    }
    __syncthreads();

    // ---- stage C: grp0 epilogue(pair0) | grp1 GEMM(pair1) then epilogue ----
    if (grp == 1) {
        do_gemm(bufB);
    }

    // epilogue: relu + row-sum; rows 0..63 -> ia, 64..127 -> ib
    // C layout 32x32: col = lane&31, row = (e&3) + 8*(e>>2) + 4*(lane>>5)
    const int ia = ibase + grp * 2;
    const int ib = ia + 1;
    float s0[2] = {0.f, 0.f}, s1[2] = {0.f, 0.f};
    #pragma unroll
    for (int mt = 0; mt < 4; ++mt)
        #pragma unroll
        for (int nt = 0; nt < 2; ++nt) {
            float t = 0.f;
            #pragma unroll
            for (int e = 0; e < 16; ++e) t += fmaxf(acc[mt][nt][e], 0.f);
            if (mt < 2) s0[nt] += t; else s1[nt] += t;
        }
    #pragma unroll
    for (int nt = 0; nt < 2; ++nt) {
        s0[nt] += __shfl_xor(s0[nt], 32);
        s1[nt] += __shfl_xor(s1[nt], 32);
    }
    if (lane < 32) {
        #pragma unroll
        for (int nt = 0; nt < 2; ++nt) {
            float sub = fmaxf(b2v[nt], 0.f);
            int col = (wn * 2 + nt) * 32 + ln;
            innode[(size_t)(b * NN + ia) * 288 + col] = (f16_t)(s0[nt] - sub);
            innode[(size_t)(b * NN + ib) * 288 + col] = (f16_t)(s1[nt] - sub);
        }
    }
}

// ------------------------------------------------------------------
// Node MLP: [8192,288] -> relu 256 -> relu 256 -> 4.
// 512 blocks x 16 rows x 256 threads (4 waves; wave = 1mt x 4nt).
// ------------------------------------------------------------------
__global__ __launch_bounds__(256, 4) void node_kernel(
    const f16_t* __restrict__ innode,  // [8192][288]
    const f16_t* __restrict__ W1op,
    const float* __restrict__ bo1,
    const f16_t* __restrict__ W2op,
    const float* __restrict__ bo2,
    const float* __restrict__ W3,      // [256][4] fp32
    const float* __restrict__ bo3,     // [4]
    float* __restrict__ out)           // [8192][4]
{
    __shared__ __align__(16) char bufA[16 * 640];
    __shared__ __align__(16) char bufB[16 * 512];
    __shared__ __align__(16) char bufC[16 * 528];

    const int tid  = threadIdx.x;
    const int lane = tid & 63;
    const int w    = tid >> 6;          // 0..3 = nt quad
    const int m0   = blockIdx.x * 16;
    const int lm   = lane & 15, lk = lane >> 4;

    for (int idx = tid; idx < 16 * 36; idx += 256) {
        int r = idx / 36, c = idx - r * 36;
        f16x8 v = *(const f16x8*)(innode + (size_t)(m0 + r) * 288 + c * 8);
        *(f16x8*)(bufA + ((r * 640 + c * 16) ^ ((r & 7) << 4))) = v;
    }
    __syncthreads();

    // ---- layer 1: K=288 (9 k-steps), bias in C-init ----
    f32x4 acc1[4];
    #pragma unroll
    for (int nt = 0; nt < 4; ++nt) {
        float bias = bo1[(w * 4 + nt) * 16 + lm];
        acc1[nt] = (f32x4){bias, bias, bias, bias};
    }
    #pragma unroll
    for (int ks = 0; ks < 9; ++ks) {
        f16x8 a = *(const f16x8*)(bufA + ((lm * 640 + ks * 64 + lk * 16) ^ ((lm & 7) << 4)));
        #pragma unroll
        for (int nt = 0; nt < 4; ++nt) {
            f16x8 bb = *(const f16x8*)(W1op + (size_t)((ks * 16 + w * 4 + nt) * 64 + lane) * 8);
            acc1[nt] = __builtin_amdgcn_mfma_f32_16x16x32_f16(a, bb, acc1[nt], 0, 0, 0);
        }
    }
    #pragma unroll
    for (int nt = 0; nt < 4; ++nt) {
        int col = (w * 4 + nt) * 16 + lm;
        #pragma unroll
        for (int j = 0; j < 4; ++j) {
            int row = lk * 4 + j;
            float v = fmaxf(acc1[nt][j], 0.f);
            *(f16_t*)(bufB + ((row * 512 + col * 2) ^ ((row & 7) << 4))) = (f16_t)v;
        }
    }
    __syncthreads();

    // ---- layer 2: K=256 (8 k-steps) ----
    f32x4 acc2[4];
    #pragma unroll
    for (int nt = 0; nt < 4; ++nt) {
        float bias = bo2[(w * 4 + nt) * 16 + lm];
        acc2[nt] = (f32x4){bias, bias, bias, bias};
    }
    #pragma unroll
    for (int ks = 0; ks < 8; ++ks) {
        f16x8 a = *(const f16x8*)(bufB + ((lm * 512 + ks * 64 + lk * 16) ^ ((lm & 7) << 4)));
        #pragma unroll
        for (int nt = 0; nt < 4; ++nt) {
            f16x8 bb = *(const f16x8*)(W2op + (size_t)((ks * 16 + w * 4 + nt) * 64 + lane) * 8);
            acc2[nt] = __builtin_amdgcn_mfma_f32_16x16x32_f16(a, bb, acc2[nt], 0, 0, 0);
        }
    }
    f16_t* c16 = (f16_t*)bufC;
    #pragma unroll
    for (int nt = 0; nt < 4; ++nt) {
        int col = (w * 4 + nt) * 16 + lm;
        #pragma unroll
        for (int j = 0; j < 4; ++j) {
            int row = lk * 4 + j;
            float v = fmaxf(acc2[nt][j], 0.f);
            c16[row * 264 + col] = (f16_t)v;
        }
    }
    __syncthreads();

    // ---- layer 3: [16,256] @ [256,4]; all 256 threads, 4-way k-split ----
    {
        int m = tid >> 4;          // 0..15
        int o = (tid >> 2) & 3;    // 0..3
        int q = tid & 3;           // k quarter
        const f16_t* crow = c16 + m * 264 + q * 64;
        float s = 0.f;
        int rot = (lane & 15) * 4; // rotate k to spread LDS banks
        #pragma unroll 8
        for (int k = 0; k < 64; ++k) {
            int kk = (k + rot) & 63;
            s += (float)crow[kk] * W3[(q * 64 + kk) * 4 + o];
        }
        s += __shfl_xor(s, 1);
        s += __shfl_xor(s, 2);
        if (q == 0) out[(size_t)(m0 + m) * 4 + o] = s + bo3[o];
    }
}

// ------------------------------------------------------------------
extern "C" void kernel_launch(void* const* d_in, const int* in_sizes, int n_in,
                              void* d_out, int out_size, void* d_ws, size_t ws_size,
                              hipStream_t stream)
{
    (void)in_sizes; (void)n_in; (void)out_size; (void)ws_size;
    const float* x      = (const float*)d_in[0];
    const float* W_msg1 = (const float*)d_in[4];
    const float* b_msg1 = (const float*)d_in[5];
    const float* W_msg2 = (const float*)d_in[6];
    const float* b_msg2 = (const float*)d_in[7];
    const float* W_out1 = (const float*)d_in[8];
    const float* b_out1 = (const float*)d_in[9];
    const float* W_out2 = (const float*)d_in[10];
    const float* b_out2 = (const float*)d_in[11];
    const float* W_out3 = (const float*)d_in[12];
    const float* b_out3 = (const float*)d_in[13];
    float* out = (float*)d_out;

    char* ws = (char*)d_ws;
    f16_t* W2p    = (f16_t*)(ws + 0);
    f16_t* W1op   = (f16_t*)(ws + 131072);
    f16_t* W2op   = (f16_t*)(ws + 278528);
    f16_t* innode = (f16_t*)(ws + 409600);
    f16_t* Vp     = (f16_t*)(ws + 5128192);
    f16_t* Up     = (f16_t*)(ws + 9322496);

    prep_all<<<1124, 256, 0, stream>>>(x, W_msg1, b_msg1, W_msg2, W_out1, W_out2,
                                       W2p, W1op, W2op, Vp, Up, innode);
    edge_kernel<<<2048, 512, 0, stream>>>(Vp, Up, W2p, b_msg2, innode);
    node_kernel<<<512, 256, 0, stream>>>(innode, W1op, b_out1, W2op, b_out2,
                                         W_out3, b_out3, out);
}

// Round 11
// 129.176 us; speedup vs baseline: 1.0003x; 1.0003x over previous
//
#include <hip/hip_runtime.h>
#include <cstddef>

typedef _Float16 f16_t;
typedef _Float16 f16x8 __attribute__((ext_vector_type(8)));
typedef float    f32x2  __attribute__((ext_vector_type(2)));
typedef float    f32x4  __attribute__((ext_vector_type(4)));
typedef float    f32x16 __attribute__((ext_vector_type(16)));

static constexpr int NN = 64;    // nodes
static constexpr int FF = 4;     // features
static constexpr int HH = 256;   // hidden

// ---- workspace layout (bytes) ----
// W2p    @ 0        : 131072   (W_msg2 packed 32x32x16 B-frags, f16)
// W1op   @ 131072   : 147456   (W_out1 padded/remapped 16x16x32, f16)
// W2op   @ 278528   : 131072   (W_out2 packed 16x16x32, f16)
// innode @ 409600   : 4718592  ([agg(256) | x(4) | pad(28)] f16, 8192 rows)
// Vp     @ 5128192  : 4194304  (V = x @ W1[4:8], f16 [128][64][256])
// Up     @ 9322496  : 4194304  (U = x @ W1[0:4] + b1, f16 [128][64][256])

// ------------------------------------------------------------------
// 16x16x32 B-frag pack: lane holds B[k=ks*32+(lane>>4)*8+j][col=nt*16+(lane&15)]
// ------------------------------------------------------------------
__device__ inline void pack_frag16(const float* __restrict__ src, f16_t* __restrict__ dst,
                                   int fid, int ksteps, int mode)
{
    if (fid >= ksteps * 1024) return;
    int lane = fid & 63;
    int nt   = (fid >> 6) & 15;
    int ks   = fid >> 10;
    int col  = nt * 16 + (lane & 15);
    int kb   = ks * 32 + (lane >> 4) * 8;
    #pragma unroll
    for (int j = 0; j < 8; ++j) {
        int k = kb + j;
        float v;
        if (mode == 0) {
            v = src[k * 256 + col];
        } else {
            if (k < 256)      v = src[(4 + k) * 256 + col];
            else if (k < 260) v = src[(k - 256) * 256 + col];
            else              v = 0.f;
        }
        dst[(size_t)fid * 8 + j] = (f16_t)v;
    }
}

// ------------------------------------------------------------------
// 32x32x16 B-frag pack: lane holds B[k=ks*16+(lane>>5)*8+j][col=nt*32+(lane&31)]
// ------------------------------------------------------------------
__device__ inline void pack_frag32(const float* __restrict__ src, f16_t* __restrict__ dst,
                                   int fid)
{
    int lane = fid & 63;
    int nt   = (fid >> 6) & 7;
    int ks   = fid >> 9;
    int col  = nt * 32 + (lane & 31);
    int kb   = ks * 16 + (lane >> 5) * 8;
    #pragma unroll
    for (int j = 0; j < 8; ++j)
        dst[(size_t)fid * 8 + j] = (f16_t)src[(kb + j) * 256 + col];
}

// ------------------------------------------------------------------
// Fused prep: weight packs + U/V precompute + innode x-tail.
// ------------------------------------------------------------------
__global__ void prep_all(const float* __restrict__ x,
                         const float* __restrict__ W_msg1,
                         const float* __restrict__ b_msg1,
                         const float* __restrict__ W_msg2,
                         const float* __restrict__ W_out1,
                         const float* __restrict__ W_out2,
                         f16_t* __restrict__ W2p, f16_t* __restrict__ W1op,
                         f16_t* __restrict__ W2op, f16_t* __restrict__ Vp,
                         f16_t* __restrict__ Up, f16_t* __restrict__ innode)
{
    int bid = blockIdx.x, tid = threadIdx.x;
    if (bid < 32) {
        pack_frag32(W_msg2, W2p, bid * 256 + tid);
    } else if (bid < 68) {
        pack_frag16(W_out1, W1op, (bid - 32) * 256 + tid, 9, 1);
    } else if (bid < 100) {
        pack_frag16(W_out2, W2op, (bid - 68) * 256 + tid, 8, 0);
    } else {
        int gid  = (bid - 100) * 256 + tid;   // 262144
        int rown = gid >> 5;                   // b*64+n
        int hb   = gid & 31;
        int h0   = hb * 8;
        float4 xv = ((const float4*)x)[rown];
        f16x8 ov, ou;
        #pragma unroll
        for (int u = 0; u < 8; ++u) {
            int h = h0 + u;
            float sv = xv.x * W_msg1[4 * HH + h] + xv.y * W_msg1[5 * HH + h]
                     + xv.z * W_msg1[6 * HH + h] + xv.w * W_msg1[7 * HH + h];
            float su = b_msg1[h]
                     + xv.x * W_msg1[0 * HH + h] + xv.y * W_msg1[1 * HH + h]
                     + xv.z * W_msg1[2 * HH + h] + xv.w * W_msg1[3 * HH + h];
            ov[u] = (f16_t)sv;
            ou[u] = (f16_t)su;
        }
        *(f16x8*)(Vp + (size_t)rown * HH + h0) = ov;
        *(f16x8*)(Up + (size_t)rown * HH + h0) = ou;
        float xt = (hb < 4) ? ((const float*)&xv)[hb] : 0.f;
        innode[(size_t)rown * 288 + 256 + hb] = (f16_t)xt;
    }
}

// ------------------------------------------------------------------
// Edge MLP + aggregation — in-register A-fragment build (no h1 phase).
// One block = (batch b, receivers i0,i1); 256 threads = 4 waves.
// Key identity: the 32x32x16 A-frag is 8 CONTIGUOUS k-elems of one
// row = one f16x8 of Up/Vp. So a = pk_max(pk_add(u8, v8), 0) builds
// A in registers inside the k-loop: VALU and MFMA interleave at
// instruction level in EVERY wave — no producer phase, no phase-lock,
// single barrier. V rows alias across mt-pairs (mt0/mt2 and mt1/mt3
// share v8) -> only 2 LDS reads + 2 broadcast U loads per k-step.
// Stage raw V (32 KB) once, swizzled chunk^(row&31) (PMC: 0 confl).
// Self rows zeroed via precomputed per-lane bools (cndmask on a);
// agg -= relu(b2) corrects the zero-row bias term.
// Wave = 4mt x 2nt, mfma_f32_32x32x16_f16, bias in C-init,
// pk-f32 epilogue (v_pk_max/add_f32 via f32x2).
// ------------------------------------------------------------------
__global__ __launch_bounds__(256, 2) void edge_kernel(
    const f16_t* __restrict__ Vp,     // [128][64][256]
    const f16_t* __restrict__ Up,     // [128][64][256]
    const f16_t* __restrict__ W2p,    // packed 32x32
    const float* __restrict__ b2,     // [256]
    f16_t* __restrict__ innode)       // [8192][288]
{
    __shared__ __align__(16) char vlds[64 * 512];   // 32 KiB raw V, swizzled

    const int tid  = threadIdx.x;
    const int lane = tid & 63;
    const int w    = tid >> 6;        // 0..3 = wn (col strip)
    const int b    = blockIdx.x >> 5;
    const int pr   = blockIdx.x & 31;
    const int i0   = pr * 2, i1 = i0 + 1;

    const f16x8* vbase = (const f16x8*)(Vp + (size_t)(b * NN) * HH);  // [64][32]

    // ---- stage raw V: 64 rows x 32 chunks of 16B, swizzled ----
    #pragma unroll
    for (int it = 0; it < 8; ++it) {
        int idx = it * 256 + tid;                 // 0..2047
        int r = idx >> 5, c = idx & 31;
        f16x8 v = vbase[idx];
        *(f16x8*)(vlds + r * 512 + (((c ^ (r & 31)) & 31) << 4)) = v;
    }

    // consumer lane mapping
    const int ln = lane & 31;     // col in ntile == A-row in mtile
    const int kh = lane >> 5;     // k-half
    const int wn = w;             // cols wn*64 .. +63

    float b2v[2];
    #pragma unroll
    for (int nt = 0; nt < 2; ++nt) b2v[nt] = b2[(wn * 2 + nt) * 32 + ln];

    const f16x8* urow0 = (const f16x8*)(Up + (size_t)(b * NN + i0) * HH);
    const f16x8* urow1 = (const f16x8*)(Up + (size_t)(b * NN + i1) * HH);

    const f16x8 fz = {};
    // self-edge lane flags per mtile (rows mt*32+ln, sender = row&63)
    const bool z0 = (i0 < 32) && (ln == i0);             // mt0: rows 0..31
    const bool z1 = (i0 >= 32) && (ln == (i0 & 31));     // mt1: rows 32..63
    const bool z2 = (i1 < 32) && (ln == i1);             // mt2: rows 64..95
    const bool z3 = (i1 >= 32) && (ln == (i1 & 31));     // mt3: rows 96..127

    // B one-ahead prefetch
    f16x8 bbn0 = *(const f16x8*)(W2p + (size_t)((wn * 2 + 0) * 64 + lane) * 8);
    f16x8 bbn1 = *(const f16x8*)(W2p + (size_t)((wn * 2 + 1) * 64 + lane) * 8);

    // acc init (bias in C)
    f32x16 acc[4][2];
    #pragma unroll
    for (int mt = 0; mt < 4; ++mt)
        #pragma unroll
        for (int nt = 0; nt < 2; ++nt)
            #pragma unroll
            for (int e = 0; e < 16; ++e) acc[mt][nt][e] = b2v[nt];

    __syncthreads();

    // ---- fused k-loop: A-build (VALU) + MFMA, co-issued per wave ----
    #pragma unroll
    for (int ks = 0; ks < 16; ++ks) {
        f16x8 bb0 = bbn0, bb1 = bbn1;
        if (ks < 15) {
            bbn0 = *(const f16x8*)(W2p + (size_t)(((ks + 1) * 8 + wn * 2 + 0) * 64 + lane) * 8);
            bbn1 = *(const f16x8*)(W2p + (size_t)(((ks + 1) * 8 + wn * 2 + 1) * 64 + lane) * 8);
        }
        const int c = ks * 2 + kh;                       // 16B chunk id
        f16x8 u0 = urow0[c];                             // broadcast-ish
        f16x8 u1 = urow1[c];
        f16x8 va = *(const f16x8*)(vlds + ln * 512 + (((c ^ ln) & 31) << 4));        // rows 0..31
        f16x8 vb = *(const f16x8*)(vlds + (32 + ln) * 512 + (((c ^ ln) & 31) << 4)); // rows 32..63

        f16x8 a0 = __builtin_elementwise_max(u0 + va, fz); if (z0) a0 = fz;
        f16x8 a1 = __builtin_elementwise_max(u0 + vb, fz); if (z1) a1 = fz;
        f16x8 a2 = __builtin_elementwise_max(u1 + va, fz); if (z2) a2 = fz;
        f16x8 a3 = __builtin_elementwise_max(u1 + vb, fz); if (z3) a3 = fz;

        acc[0][0] = __builtin_amdgcn_mfma_f32_32x32x16_f16(a0, bb0, acc[0][0], 0, 0, 0);
        acc[0][1] = __builtin_amdgcn_mfma_f32_32x32x16_f16(a0, bb1, acc[0][1], 0, 0, 0);
        acc[1][0] = __builtin_amdgcn_mfma_f32_32x32x16_f16(a1, bb0, acc[1][0], 0, 0, 0);
        acc[1][1] = __builtin_amdgcn_mfma_f32_32x32x16_f16(a1, bb1, acc[1][1], 0, 0, 0);
        acc[2][0] = __builtin_amdgcn_mfma_f32_32x32x16_f16(a2, bb0, acc[2][0], 0, 0, 0);
        acc[2][1] = __builtin_amdgcn_mfma_f32_32x32x16_f16(a2, bb1, acc[2][1], 0, 0, 0);
        acc[3][0] = __builtin_amdgcn_mfma_f32_32x32x16_f16(a3, bb0, acc[3][0], 0, 0, 0);
        acc[3][1] = __builtin_amdgcn_mfma_f32_32x32x16_f16(a3, bb1, acc[3][1], 0, 0, 0);
    }

    // ---- epilogue: packed-f32 relu + row-sum ----
    // C layout 32x32: col = lane&31, row = (e&3) + 8*(e>>2) + 4*kh
    const f32x2 zz = {0.f, 0.f};
    f32x2 p0[2] = {zz, zz}, p1[2] = {zz, zz};
    #pragma unroll
    for (int mt = 0; mt < 4; ++mt)
        #pragma unroll
        for (int nt = 0; nt < 2; ++nt) {
            f32x2 t = zz;
            #pragma unroll
            for (int h = 0; h < 8; ++h) {
                f32x2 e = __builtin_shufflevector(acc[mt][nt], acc[mt][nt], 0, 1);
                // rebuild with correct indices per h (constant):
                switch (h) {
                    case 0: e = __builtin_shufflevector(acc[mt][nt], acc[mt][nt], 0, 1); break;
                    case 1: e = __builtin_shufflevector(acc[mt][nt], acc[mt][nt], 2, 3); break;
                    case 2: e = __builtin_shufflevector(acc[mt][nt], acc[mt][nt], 4, 5); break;
                    case 3: e = __builtin_shufflevector(acc[mt][nt], acc[mt][nt], 6, 7); break;
                    case 4: e = __builtin_shufflevector(acc[mt][nt], acc[mt][nt], 8, 9); break;
                    case 5: e = __builtin_shufflevector(acc[mt][nt], acc[mt][nt], 10, 11); break;
                    case 6: e = __builtin_shufflevector(acc[mt][nt], acc[mt][nt], 12, 13); break;
                    case 7: e = __builtin_shufflevector(acc[mt][nt], acc[mt][nt], 14, 15); break;
                }
                t += __builtin_elementwise_max(e, zz);
            }
            if (mt < 2) p0[nt] += t; else p1[nt] += t;
        }
    float s0[2] = {p0[0].x + p0[0].y, p0[1].x + p0[1].y};
    float s1[2] = {p1[0].x + p1[0].y, p1[1].x + p1[1].y};
    #pragma unroll
    for (int nt = 0; nt < 2; ++nt) {
        s0[nt] += __shfl_xor(s0[nt], 32);
        s1[nt] += __shfl_xor(s1[nt], 32);
    }
    if (lane < 32) {
        #pragma unroll
        for (int nt = 0; nt < 2; ++nt) {
            float sub = fmaxf(b2v[nt], 0.f);    // zeroed self row -> relu(b2) term
            int col = (wn * 2 + nt) * 32 + ln;
            innode[(size_t)(b * NN + i0) * 288 + col] = (f16_t)(s0[nt] - sub);
            innode[(size_t)(b * NN + i1) * 288 + col] = (f16_t)(s1[nt] - sub);
        }
    }
}

// ------------------------------------------------------------------
// Node MLP: [8192,288] -> relu 256 -> relu 256 -> 4.
// 512 blocks x 16 rows x 256 threads (4 waves; wave = 1mt x 4nt).
// ------------------------------------------------------------------
__global__ __launch_bounds__(256, 4) void node_kernel(
    const f16_t* __restrict__ innode,  // [8192][288]
    const f16_t* __restrict__ W1op,
    const float* __restrict__ bo1,
    const f16_t* __restrict__ W2op,
    const float* __restrict__ bo2,
    const float* __restrict__ W3,      // [256][4] fp32
    const float* __restrict__ bo3,     // [4]
    float* __restrict__ out)           // [8192][4]
{
    __shared__ __align__(16) char bufA[16 * 640];
    __shared__ __align__(16) char bufB[16 * 512];
    __shared__ __align__(16) char bufC[16 * 528];

    const int tid  = threadIdx.x;
    const int lane = tid & 63;
    const int w    = tid >> 6;          // 0..3 = nt quad
    const int m0   = blockIdx.x * 16;
    const int lm   = lane & 15, lk = lane >> 4;

    for (int idx = tid; idx < 16 * 36; idx += 256) {
        int r = idx / 36, c = idx - r * 36;
        f16x8 v = *(const f16x8*)(innode + (size_t)(m0 + r) * 288 + c * 8);
        *(f16x8*)(bufA + ((r * 640 + c * 16) ^ ((r & 7) << 4))) = v;
    }
    __syncthreads();

    // ---- layer 1: K=288 (9 k-steps), bias in C-init ----
    f32x4 acc1[4];
    #pragma unroll
    for (int nt = 0; nt < 4; ++nt) {
        float bias = bo1[(w * 4 + nt) * 16 + lm];
        acc1[nt] = (f32x4){bias, bias, bias, bias};
    }
    #pragma unroll
    for (int ks = 0; ks < 9; ++ks) {
        f16x8 a = *(const f16x8*)(bufA + ((lm * 640 + ks * 64 + lk * 16) ^ ((lm & 7) << 4)));
        #pragma unroll
        for (int nt = 0; nt < 4; ++nt) {
            f16x8 bb = *(const f16x8*)(W1op + (size_t)((ks * 16 + w * 4 + nt) * 64 + lane) * 8);
            acc1[nt] = __builtin_amdgcn_mfma_f32_16x16x32_f16(a, bb, acc1[nt], 0, 0, 0);
        }
    }
    #pragma unroll
    for (int nt = 0; nt < 4; ++nt) {
        int col = (w * 4 + nt) * 16 + lm;
        #pragma unroll
        for (int j = 0; j < 4; ++j) {
            int row = lk * 4 + j;
            float v = fmaxf(acc1[nt][j], 0.f);
            *(f16_t*)(bufB + ((row * 512 + col * 2) ^ ((row & 7) << 4))) = (f16_t)v;
        }
    }
    __syncthreads();

    // ---- layer 2: K=256 (8 k-steps) ----
    f32x4 acc2[4];
    #pragma unroll
    for (int nt = 0; nt < 4; ++nt) {
        float bias = bo2[(w * 4 + nt) * 16 + lm];
        acc2[nt] = (f32x4){bias, bias, bias, bias};
    }
    #pragma unroll
    for (int ks = 0; ks < 8; ++ks) {
        f16x8 a = *(const f16x8*)(bufB + ((lm * 512 + ks * 64 + lk * 16) ^ ((lm & 7) << 4)));
        #pragma unroll
        for (int nt = 0; nt < 4; ++nt) {
            f16x8 bb = *(const f16x8*)(W2op + (size_t)((ks * 16 + w * 4 + nt) * 64 + lane) * 8);
            acc2[nt] = __builtin_amdgcn_mfma_f32_16x16x32_f16(a, bb, acc2[nt], 0, 0, 0);
        }
    }
    f16_t* c16 = (f16_t*)bufC;
    #pragma unroll
    for (int nt = 0; nt < 4; ++nt) {
        int col = (w * 4 + nt) * 16 + lm;
        #pragma unroll
        for (int j = 0; j < 4; ++j) {
            int row = lk * 4 + j;
            float v = fmaxf(acc2[nt][j], 0.f);
            c16[row * 264 + col] = (f16_t)v;
        }
    }
    __syncthreads();

    // ---- layer 3: [16,256] @ [256,4]; all 256 threads, 4-way k-split ----
    {
        int m = tid >> 4;          // 0..15
        int o = (tid >> 2) & 3;    // 0..3
        int q = tid & 3;           // k quarter
        const f16_t* crow = c16 + m * 264 + q * 64;
        float s = 0.f;
        int rot = (lane & 15) * 4; // rotate k to spread LDS banks
        #pragma unroll 8
        for (int k = 0; k < 64; ++k) {
            int kk = (k + rot) & 63;
            s += (float)crow[kk] * W3[(q * 64 + kk) * 4 + o];
        }
        s += __shfl_xor(s, 1);
        s += __shfl_xor(s, 2);
        if (q == 0) out[(size_t)(m0 + m) * 4 + o] = s + bo3[o];
    }
}

// ------------------------------------------------------------------
extern "C" void kernel_launch(void* const* d_in, const int* in_sizes, int n_in,
                              void* d_out, int out_size, void* d_ws, size_t ws_size,
                              hipStream_t stream)
{
    (void)in_sizes; (void)n_in; (void)out_size; (void)ws_size;
    const float* x      = (const float*)d_in[0];
    const float* W_msg1 = (const float*)d_in[4];
    const float* b_msg1 = (const float*)d_in[5];
    const float* W_msg2 = (const float*)d_in[6];
    const float* b_msg2 = (const float*)d_in[7];
    const float* W_out1 = (const float*)d_in[8];
    const float* b_out1 = (const float*)d_in[9];
    const float* W_out2 = (const float*)d_in[10];
    const float* b_out2 = (const float*)d_in[11];
    const float* W_out3 = (const float*)d_in[12];
    const float* b_out3 = (const float*)d_in[13];
    float* out = (float*)d_out;

    char* ws = (char*)d_ws;
    f16_t* W2p    = (f16_t*)(ws + 0);
    f16_t* W1op   = (f16_t*)(ws + 131072);
    f16_t* W2op   = (f16_t*)(ws + 278528);
    f16_t* innode = (f16_t*)(ws + 409600);
    f16_t* Vp     = (f16_t*)(ws + 5128192);
    f16_t* Up     = (f16_t*)(ws + 9322496);

    prep_all<<<1124, 256, 0, stream>>>(x, W_msg1, b_msg1, W_msg2, W_out1, W_out2,
                                       W2p, W1op, W2op, Vp, Up, innode);
    edge_kernel<<<4096, 256, 0, stream>>>(Vp, Up, W2p, b_msg2, innode);
    node_kernel<<<512, 256, 0, stream>>>(innode, W1op, b_out1, W2op, b_out2,
                                         W_out3, b_out3, out);
}

// Round 12
// 95.861 us; speedup vs baseline: 1.3480x; 1.3475x over previous
//
#include <hip/hip_runtime.h>
#include <cstddef>

typedef _Float16 f16_t;
typedef _Float16 f16x8 __attribute__((ext_vector_type(8)));
typedef float    f32x2  __attribute__((ext_vector_type(2)));
typedef float    f32x4  __attribute__((ext_vector_type(4)));
typedef float    f32x16 __attribute__((ext_vector_type(16)));

static constexpr int NN = 64;    // nodes
static constexpr int FF = 4;     // features
static constexpr int HH = 256;   // hidden

// ---- workspace layout (bytes) ----
// W2p    @ 0       : 131072   (W_msg2 packed 32x32x16 B-frags, f16)
// W1op   @ 131072  : 147456   (W_out1 padded/remapped 16x16x32, f16)
// W2op   @ 278528  : 131072   (W_out2 packed 16x16x32, f16)
// innode @ 409600  : 4718592  ([agg(256) | x(4) | pad(28)] f16, 8192 rows)
// Vp     @ 5128192 : 4194304  (V = x @ W1[4:8], f16 [128][64][256])

// ------------------------------------------------------------------
// 16x16x32 B-frag pack: lane holds B[k=ks*32+(lane>>4)*8+j][col=nt*16+(lane&15)]
// ------------------------------------------------------------------
__device__ inline void pack_frag16(const float* __restrict__ src, f16_t* __restrict__ dst,
                                   int fid, int ksteps, int mode)
{
    if (fid >= ksteps * 1024) return;
    int lane = fid & 63;
    int nt   = (fid >> 6) & 15;
    int ks   = fid >> 10;
    int col  = nt * 16 + (lane & 15);
    int kb   = ks * 32 + (lane >> 4) * 8;
    #pragma unroll
    for (int j = 0; j < 8; ++j) {
        int k = kb + j;
        float v;
        if (mode == 0) {
            v = src[k * 256 + col];
        } else {
            if (k < 256)      v = src[(4 + k) * 256 + col];
            else if (k < 260) v = src[(k - 256) * 256 + col];
            else              v = 0.f;
        }
        dst[(size_t)fid * 8 + j] = (f16_t)v;
    }
}

// ------------------------------------------------------------------
// 32x32x16 B-frag pack: lane holds B[k=ks*16+(lane>>5)*8+j][col=nt*32+(lane&31)]
// ------------------------------------------------------------------
__device__ inline void pack_frag32(const float* __restrict__ src, f16_t* __restrict__ dst,
                                   int fid)
{
    int lane = fid & 63;
    int nt   = (fid >> 6) & 7;
    int ks   = fid >> 9;
    int col  = nt * 32 + (lane & 31);
    int kb   = ks * 16 + (lane >> 5) * 8;
    #pragma unroll
    for (int j = 0; j < 8; ++j)
        dst[(size_t)fid * 8 + j] = (f16_t)src[(kb + j) * 256 + col];
}

// ------------------------------------------------------------------
// Fused prep: weight packs + V precompute.
// blocks [0,32): W2p(32x32)  [32,68): W1op  [68,100): W2op  [100,1124): Vp
// ------------------------------------------------------------------
__global__ void prep_all(const float* __restrict__ x,
                         const float* __restrict__ W_msg1,
                         const float* __restrict__ W_msg2,
                         const float* __restrict__ W_out1,
                         const float* __restrict__ W_out2,
                         f16_t* __restrict__ W2p, f16_t* __restrict__ W1op,
                         f16_t* __restrict__ W2op, f16_t* __restrict__ Vp)
{
    int bid = blockIdx.x, tid = threadIdx.x;
    if (bid < 32) {
        pack_frag32(W_msg2, W2p, bid * 256 + tid);
    } else if (bid < 68) {
        pack_frag16(W_out1, W1op, (bid - 32) * 256 + tid, 9, 1);
    } else if (bid < 100) {
        pack_frag16(W_out2, W2op, (bid - 68) * 256 + tid, 8, 0);
    } else {
        int gid  = (bid - 100) * 256 + tid;   // 262144
        int rown = gid >> 5;                   // b*64+n
        int h0   = (gid & 31) * 8;
        float4 xv = ((const float4*)x)[rown];
        f16x8 o;
        #pragma unroll
        for (int u = 0; u < 8; ++u) {
            float s = xv.x * W_msg1[4 * HH + h0 + u] + xv.y * W_msg1[5 * HH + h0 + u]
                    + xv.z * W_msg1[6 * HH + h0 + u] + xv.w * W_msg1[7 * HH + h0 + u];
            o[u] = (f16_t)s;
        }
        *(f16x8*)(Vp + (size_t)rown * HH + h0) = o;
    }
}

// ------------------------------------------------------------------
// Edge MLP + aggregation — R6 structure (best measured: 71.5 us).
// One block = (batch b, receivers i0,i1); 256 threads = 4 waves.
// h1[r] = relu(U_recv + V_j) packed fp16; U table in LDS; h1 in LDS
// [128 rows][32 chunks], swizzle chunk^(r&31) (PMC-verified 0 confl).
// GEMM: mfma_f32_32x32x16_f16, wave = 4mt x 2nt (W2p read once per
// block = 128 KB), bias in MFMA C-init, B one-ahead prefetch.
// Self rows zeroed; agg corrected by subtracting relu(b2).
// Epilogue: packed-f32 relu+rowsum (R11-verified correct).
// Register wall note: VGPR 124 + AGPR 128 = 252/wave at the
// launch_bounds(256,2) cap of 256 — no headroom for deeper prefetch;
// R5/R7/R8/R9/R10/R11 alternatives all regressed (see journal).
// ------------------------------------------------------------------
__global__ __launch_bounds__(256, 2) void edge_kernel(
    const float* __restrict__ x,      // [128][64][4]
    const float* __restrict__ W1,     // [8][256]
    const float* __restrict__ b1,     // [256]
    const f16_t* __restrict__ Vp,     // [128][64][256]
    const f16_t* __restrict__ W2p,    // packed 32x32
    const float* __restrict__ b2,     // [256]
    f16_t* __restrict__ innode)       // [8192][288]
{
    __shared__ __align__(16) char h1[128 * 512];   // 64 KiB f16, swizzled
    __shared__ __align__(16) f16_t Utab[2][256];

    const int tid  = threadIdx.x;
    const int lane = tid & 63;
    const int w    = tid >> 6;        // 0..3 = wn (col strip)
    const int b    = blockIdx.x >> 5;
    const int pr   = blockIdx.x & 31;
    const int i0   = pr * 2, i1 = i0 + 1;

    // ---- U table: 512 entries, 2 per thread ----
    #pragma unroll
    for (int i = 0; i < 2; ++i) {
        int e    = tid + i * 256;
        int rs   = e >> 8;                // 0 -> i0, 1 -> i1
        int h    = e & 255;
        int node = rs ? i1 : i0;
        const float* xr = x + (b * NN + node) * FF;
        float s = b1[h] + xr[0] * W1[h] + xr[1] * W1[HH + h]
                        + xr[2] * W1[2 * HH + h] + xr[3] * W1[3 * HH + h];
        Utab[rs][h] = (f16_t)s;
    }
    // x + zero-pad tail columns 256..287 of innode
    if (tid < 64) {
        int node = (tid < 32) ? i0 : i1;
        int c = tid & 31;
        float v = (c < 4) ? x[(b * NN + node) * FF + c] : 0.f;
        innode[(size_t)(b * NN + node) * 288 + 256 + c] = (f16_t)v;
    }
    __syncthreads();

    // ---- h1: thread = (row-group rg 0..7, 16 rows) x (8-col block hb) ----
    {
        const int hb = tid & 31;
        const int rg = tid >> 5;
        const int h0 = hb * 8;
        const int recv = (rg < 4) ? i0 : i1;
        const f16x8 fz = {};
        f16x8 u8 = *(const f16x8*)&Utab[rg >> 2][h0];
        const int j0 = (rg & 3) * 16;
        const f16x8* vrow = (const f16x8*)(Vp + (size_t)(b * NN + j0) * HH + h0);
        #pragma unroll
        for (int k = 0; k < 16; ++k) {
            int r = rg * 16 + k;          // j = j0 + k = r & 63
            f16x8 v8 = vrow[k * (HH / 8)];
            f16x8 hv = __builtin_elementwise_max(u8 + v8, fz);
            *(f16x8*)(h1 + r * 512 + (((hb ^ (r & 31)) & 31) << 4)) = hv;
        }
        // self edge: row where sender j == recv (uniform branch, 1/4 of threads)
        if ((rg & 3) == (recv >> 4)) {
            int r = rg * 16 + (recv & 15);
            *(f16x8*)(h1 + r * 512 + (((hb ^ (r & 31)) & 31) << 4)) = fz;
        }
    }
    __syncthreads();

    // ---- layer 2: [128,256] @ [256,256] via 32x32x16; wave = 4mt x 2nt ----
    const int ln = lane & 31;     // col within ntile
    const int kh = lane >> 5;     // k-half selector
    const int wn = w;             // col strip: cols wn*64 .. +63

    float b2v[2];
    #pragma unroll
    for (int nt = 0; nt < 2; ++nt) b2v[nt] = b2[(wn * 2 + nt) * 32 + ln];

    f32x16 acc[4][2];
    #pragma unroll
    for (int mt = 0; mt < 4; ++mt)
        #pragma unroll
        for (int nt = 0; nt < 2; ++nt)
            #pragma unroll
            for (int e = 0; e < 16; ++e) acc[mt][nt][e] = b2v[nt];

    f16x8 bbn0 = *(const f16x8*)(W2p + (size_t)((wn * 2 + 0) * 64 + lane) * 8);
    f16x8 bbn1 = *(const f16x8*)(W2p + (size_t)((wn * 2 + 1) * 64 + lane) * 8);
    #pragma unroll
    for (int ks = 0; ks < 16; ++ks) {
        f16x8 bb0 = bbn0, bb1 = bbn1;
        if (ks < 15) {
            bbn0 = *(const f16x8*)(W2p + (size_t)(((ks + 1) * 8 + wn * 2 + 0) * 64 + lane) * 8);
            bbn1 = *(const f16x8*)(W2p + (size_t)(((ks + 1) * 8 + wn * 2 + 1) * 64 + lane) * 8);
        }
        #pragma unroll
        for (int mt = 0; mt < 4; ++mt) {
            int row = mt * 32 + ln;
            int c16 = (ks * 2 + kh) ^ (row & 31);
            f16x8 a = *(const f16x8*)(h1 + row * 512 + (c16 << 4));
            acc[mt][0] = __builtin_amdgcn_mfma_f32_32x32x16_f16(a, bb0, acc[mt][0], 0, 0, 0);
            acc[mt][1] = __builtin_amdgcn_mfma_f32_32x32x16_f16(a, bb1, acc[mt][1], 0, 0, 0);
        }
    }

    // ---- epilogue: packed-f32 relu + row-sum (R11-verified) ----
    // C layout 32x32: col = lane&31, row = (e&3) + 8*(e>>2) + 4*kh
    const f32x2 zz = {0.f, 0.f};
    f32x2 p0[2] = {zz, zz}, p1[2] = {zz, zz};
    #pragma unroll
    for (int mt = 0; mt < 4; ++mt)
        #pragma unroll
        for (int nt = 0; nt < 2; ++nt) {
            f32x2 t = zz;
            #pragma unroll
            for (int h = 0; h < 8; ++h) {
                f32x2 e;
                switch (h) {
                    case 0: e = __builtin_shufflevector(acc[mt][nt], acc[mt][nt], 0, 1); break;
                    case 1: e = __builtin_shufflevector(acc[mt][nt], acc[mt][nt], 2, 3); break;
                    case 2: e = __builtin_shufflevector(acc[mt][nt], acc[mt][nt], 4, 5); break;
                    case 3: e = __builtin_shufflevector(acc[mt][nt], acc[mt][nt], 6, 7); break;
                    case 4: e = __builtin_shufflevector(acc[mt][nt], acc[mt][nt], 8, 9); break;
                    case 5: e = __builtin_shufflevector(acc[mt][nt], acc[mt][nt], 10, 11); break;
                    case 6: e = __builtin_shufflevector(acc[mt][nt], acc[mt][nt], 12, 13); break;
                    default: e = __builtin_shufflevector(acc[mt][nt], acc[mt][nt], 14, 15); break;
                }
                t += __builtin_elementwise_max(e, zz);
            }
            if (mt < 2) p0[nt] += t; else p1[nt] += t;
        }
    float s0[2] = {p0[0].x + p0[0].y, p0[1].x + p0[1].y};
    float s1[2] = {p1[0].x + p1[0].y, p1[1].x + p1[1].y};
    #pragma unroll
    for (int nt = 0; nt < 2; ++nt) {
        s0[nt] += __shfl_xor(s0[nt], 32);
        s1[nt] += __shfl_xor(s1[nt], 32);
    }
    if (lane < 32) {
        #pragma unroll
        for (int nt = 0; nt < 2; ++nt) {
            float sub = fmaxf(b2v[nt], 0.f);
            int col = (wn * 2 + nt) * 32 + ln;
            innode[(size_t)(b * NN + i0) * 288 + col] = (f16_t)(s0[nt] - sub);
            innode[(size_t)(b * NN + i1) * 288 + col] = (f16_t)(s1[nt] - sub);
        }
    }
}

// ------------------------------------------------------------------
// Node MLP: [8192,288] -> relu 256 -> relu 256 -> 4.
// 256 blocks x 32 rows x 512 threads (R3 version — best non-edge):
// halves per-block weight L2 re-reads vs 512-block/16-row variant.
// ------------------------------------------------------------------
__global__ __launch_bounds__(512, 2) void node_kernel(
    const f16_t* __restrict__ innode,  // [8192][288]
    const f16_t* __restrict__ W1op,
    const float* __restrict__ bo1,
    const f16_t* __restrict__ W2op,
    const float* __restrict__ bo2,
    const float* __restrict__ W3,      // [256][4] fp32
    const float* __restrict__ bo3,     // [4]
    float* __restrict__ out)           // [8192][4]
{
    __shared__ __align__(16) char bufA[32 * 640];
    __shared__ __align__(16) char bufB[32 * 512];
    __shared__ __align__(16) char bufC[32 * 528];

    const int tid  = threadIdx.x;
    const int lane = tid & 63;
    const int w    = tid >> 6;
    const int m0   = blockIdx.x * 32;
    const int lm   = lane & 15, lk = lane >> 4;
    const int mt   = w >> 2;           // 0..1 (16-row half)
    const int ntq  = w & 3;            // 0..3 (4 ntiles)

    for (int idx = tid; idx < 32 * 36; idx += 512) {
        int r = idx / 36, c = idx - r * 36;
        f16x8 v = *(const f16x8*)(innode + (size_t)(m0 + r) * 288 + c * 8);
        *(f16x8*)(bufA + ((r * 640 + c * 16) ^ ((r & 7) << 4))) = v;
    }
    __syncthreads();

    // ---- layer 1: K=288 (9 k-steps), bias in C-init ----
    f32x4 acc1[4];
    #pragma unroll
    for (int nt = 0; nt < 4; ++nt) {
        float bias = bo1[(ntq * 4 + nt) * 16 + lm];
        acc1[nt] = (f32x4){bias, bias, bias, bias};
    }
    #pragma unroll
    for (int ks = 0; ks < 9; ++ks) {
        int r = mt * 16 + lm;
        f16x8 a = *(const f16x8*)(bufA + ((r * 640 + ks * 64 + lk * 16) ^ ((r & 7) << 4)));
        #pragma unroll
        for (int nt = 0; nt < 4; ++nt) {
            f16x8 bb = *(const f16x8*)(W1op + (size_t)((ks * 16 + ntq * 4 + nt) * 64 + lane) * 8);
            acc1[nt] = __builtin_amdgcn_mfma_f32_16x16x32_f16(a, bb, acc1[nt], 0, 0, 0);
        }
    }
    #pragma unroll
    for (int nt = 0; nt < 4; ++nt) {
        int col = (ntq * 4 + nt) * 16 + lm;
        #pragma unroll
        for (int j = 0; j < 4; ++j) {
            int row = mt * 16 + lk * 4 + j;
            float v = fmaxf(acc1[nt][j], 0.f);
            *(f16_t*)(bufB + ((row * 512 + col * 2) ^ ((row & 7) << 4))) = (f16_t)v;
        }
    }
    __syncthreads();

    // ---- layer 2: K=256 (8 k-steps) ----
    f32x4 acc2[4];
    #pragma unroll
    for (int nt = 0; nt < 4; ++nt) {
        float bias = bo2[(ntq * 4 + nt) * 16 + lm];
        acc2[nt] = (f32x4){bias, bias, bias, bias};
    }
    #pragma unroll
    for (int ks = 0; ks < 8; ++ks) {
        int r = mt * 16 + lm;
        f16x8 a = *(const f16x8*)(bufB + ((r * 512 + ks * 64 + lk * 16) ^ ((r & 7) << 4)));
        #pragma unroll
        for (int nt = 0; nt < 4; ++nt) {
            f16x8 bb = *(const f16x8*)(W2op + (size_t)((ks * 16 + ntq * 4 + nt) * 64 + lane) * 8);
            acc2[nt] = __builtin_amdgcn_mfma_f32_16x16x32_f16(a, bb, acc2[nt], 0, 0, 0);
        }
    }
    f16_t* c16 = (f16_t*)bufC;
    #pragma unroll
    for (int nt = 0; nt < 4; ++nt) {
        int col = (ntq * 4 + nt) * 16 + lm;
        #pragma unroll
        for (int j = 0; j < 4; ++j) {
            int row = mt * 16 + lk * 4 + j;
            float v = fmaxf(acc2[nt][j], 0.f);
            c16[row * 264 + col] = (f16_t)v;
        }
    }
    __syncthreads();

    // ---- layer 3: [32,256] @ [256,4]; all 512 threads, 4-way k-split ----
    {
        int m = tid >> 4;          // 0..31
        int o = (tid >> 2) & 3;    // 0..3
        int q = tid & 3;           // k quarter
        const f16_t* crow = c16 + m * 264 + q * 64;
        float s = 0.f;
        int rot = (lane & 15) * 4; // rotate k to spread LDS banks
        #pragma unroll 8
        for (int k = 0; k < 64; ++k) {
            int kk = (k + rot) & 63;
            s += (float)crow[kk] * W3[(q * 64 + kk) * 4 + o];
        }
        s += __shfl_xor(s, 1);
        s += __shfl_xor(s, 2);
        if (q == 0) out[(size_t)(m0 + m) * 4 + o] = s + bo3[o];
    }
}

// ------------------------------------------------------------------
extern "C" void kernel_launch(void* const* d_in, const int* in_sizes, int n_in,
                              void* d_out, int out_size, void* d_ws, size_t ws_size,
                              hipStream_t stream)
{
    (void)in_sizes; (void)n_in; (void)out_size; (void)ws_size;
    const float* x      = (const float*)d_in[0];
    const float* W_msg1 = (const float*)d_in[4];
    const float* b_msg1 = (const float*)d_in[5];
    const float* W_msg2 = (const float*)d_in[6];
    const float* b_msg2 = (const float*)d_in[7];
    const float* W_out1 = (const float*)d_in[8];
    const float* b_out1 = (const float*)d_in[9];
    const float* W_out2 = (const float*)d_in[10];
    const float* b_out2 = (const float*)d_in[11];
    const float* W_out3 = (const float*)d_in[12];
    const float* b_out3 = (const float*)d_in[13];
    float* out = (float*)d_out;

    char* ws = (char*)d_ws;
    f16_t* W2p    = (f16_t*)(ws + 0);
    f16_t* W1op   = (f16_t*)(ws + 131072);
    f16_t* W2op   = (f16_t*)(ws + 278528);
    f16_t* innode = (f16_t*)(ws + 409600);
    f16_t* Vp     = (f16_t*)(ws + 5128192);

    prep_all<<<1124, 256, 0, stream>>>(x, W_msg1, W_msg2, W_out1, W_out2,
                                       W2p, W1op, W2op, Vp);
    edge_kernel<<<4096, 256, 0, stream>>>(x, W_msg1, b_msg1, Vp, W2p, b_msg2, innode);
    node_kernel<<<256, 512, 0, stream>>>(innode, W1op, b_out1, W2op, b_out2,
                                         W_out3, b_out3, out);
}